// Round 4
// baseline (402.881 us; speedup 1.0000x reference)
//
#include <hip/hip_runtime.h>
#include <math.h>

#define H 320
#define W 640
#define C 32
#define HW (H * W)
#define HWC (H * W * C)
#define FILLV 1e9f

// Tile geometry: 8x8 inner, ext1 = 10x10 (m2 range), ext2 = 12x12 (m1 range).
#define TX 8
#define TY 8
#define E1 10
#define E2 12
#define PSTR 32               // label stride (floats)

#define NTILE_X (W / TX)      // 80
#define NTILE_Y (H / TY)      // 40
#define NTILES (NTILE_X * NTILE_Y)   // 3200

// Persistent launch: 768 blocks = 3 blocks x 256 CUs exactly (LDS 51.2 KB
// -> 3 blocks/CU is the residency cap). Each block loops 4-5 tiles.
#define BLOCK 576             // 9 waves: stage-1 1152 tasks = exactly 2 passes
#define NBLK 768
#define S1_TASKS (E2 * E2 * 8)     // 1152
#define S2_TASKS (E1 * E1 * 8)     // 800

static_assert(S1_TASKS == 2 * BLOCK, "stage-1 must be exactly two full passes");

// ---- DPP cross-lane (VALU pipe) ----
template <int CTRL>
__device__ __forceinline__ float dppf(float x) {
    int r = __builtin_amdgcn_update_dpp(0, __builtin_bit_cast(int, x),
                                        CTRL, 0xF, 0xF, true);
    return __builtin_bit_cast(float, r);
}
#define DPP_XOR1   0xB1    // quad_perm [1,0,3,2]  : lane i <- i^1
#define DPP_XOR2   0x4E    // quad_perm [2,3,0,1]  : lane i <- i^2
#define DPP_MIRR8  0x141   // row_half_mirror      : lane i <- i^7
#define DPP_UP1    0x111   // row_shr:1            : lane i <- i-1
#define DPP_DN1    0x101   // row_shl:1            : lane i <- i+1

__device__ __forceinline__ float gmin8(float v) {
    v = fminf(v, dppf<DPP_XOR1>(v));
    v = fminf(v, dppf<DPP_XOR2>(v));
    v = fminf(v, dppf<DPP_MIRR8>(v));
    return v;
}
__device__ __forceinline__ float gmax8(float v) {
    v = fmaxf(v, dppf<DPP_XOR1>(v));
    v = fmaxf(v, dppf<DPP_XOR2>(v));
    v = fmaxf(v, dppf<DPP_MIRR8>(v));
    return v;
}
__device__ __forceinline__ float gsum8(float v) {
    v += dppf<DPP_XOR1>(v);
    v += dppf<DPP_XOR2>(v);
    v += dppf<DPP_MIRR8>(v);
    return v;
}

// Nontemporal float4 store: keep the 131 MB message/belief write stream from
// evicting the read-side halo working set out of L2.
typedef float vfloat4 __attribute__((ext_vector_type(4)));
__device__ __forceinline__ void nt_store4(float* p, float x, float y, float z, float w) {
    vfloat4 v; v.x = x; v.y = y; v.z = z; v.w = w;
    __builtin_nontemporal_store(v, (vfloat4*)p);
}

// Truncated-linear min-sum core over 32 labels (4/lane x 8 lanes).
// RESCALE subtracts hmin — exact analytic min (weights >= 0). Unrescaled
// intermediates differ from the reference by a per-pixel label-constant,
// which cancels in any downstream rescaled message.
template <bool RESCALE>
__device__ __forceinline__ void msg_core(
    float h0, float h1, float h2, float h3, int q,
    float w_p1, float w_m1, float w_L2,
    float& m0, float& m1, float& m2, float& m3)
{
    const float up = dppf<DPP_UP1>(h3);     // lane q-1's label 4q-1
    const float dn = dppf<DPP_DN1>(h0);     // lane q+1's label 4q+4
    const float lm0 = (q == 0) ? FILLV : up;
    const float lp3 = (q == 7) ? FILLV : dn;

    float hmin = gmin8(fminf(fminf(h0, h1), fminf(h2, h3)));
    const float tr = hmin + w_L2;
    const float sub = RESCALE ? hmin : 0.f;

    m0 = fminf(fminf(h0, lm0 + w_p1), fminf(h1 + w_m1, tr)) - sub;
    m1 = fminf(fminf(h1, h0  + w_p1), fminf(h2 + w_m1, tr)) - sub;
    m2 = fminf(fminf(h2, h1  + w_p1), fminf(h3 + w_m1, tr)) - sub;
    m3 = fminf(fminf(h3, h2  + w_p1), fminf(lp3 + w_m1, tr)) - sub;
}

// d: 0 -> sender at x-1 (boundary x==0), 1 -> x+1, 2 -> y-1, 3 -> y+1.
__device__ __forceinline__ bool sender_of(int x, int y, int d, int& sx, int& sy) {
    sx = x; sy = y;
    if (d == 0) { sx = x - 1; return x == 0; }
    if (d == 1) { sx = x + 1; return x == W - 1; }
    if (d == 2) { sy = y - 1; return y == 0; }
    sy = y + 1; return y == H - 1;
}

// Shared tile pipeline. INTERIOR=true compiles away every OOB / image-border
// guard (valid whenever the tile's stage-1 reach [bx0-3,bx0+10]x[by0-3,by0+10]
// is in-bounds). With BLOCK=576, stage 1 is exactly two full straight-line
// passes — no task-validity branch, no straggler pass at the barrier.
template <bool INTERIOR>
__device__ __forceinline__ void bp_tile(
    const int bx0, const int by0, const int tid,
    const float* __restrict__ prob_vol, const float* __restrict__ edge,
    const float* __restrict__ aff, float* __restrict__ msg_out,
    float* __restrict__ beliefs, float* hbuf)
{
    const int q = tid & 7;
    const int lbase = 4 * q;

    // ---- stage 1: m1 at ext2 (12x12), scatter h2 = T1 - m1[dd] to the
    //      ext1 receiver in direction dd (plane dd^1).
    #pragma unroll
    for (int pass = 0; pass < 2; ++pass) {
        const int task = tid + BLOCK * pass;     // always < S1_TASKS
        const int e  = task >> 3;
        const int ex = e % E2;
        const int ey = e / E2;
        const int gx = bx0 + ex - 2;
        const int gy = by0 + ey - 2;
        if (!INTERIOR && (gx < 0 || gx >= W || gy < 0 || gy >= H)) continue;

        const int sp = gy * W + gx;
        const float4 cs = *(const float4*)(prob_vol + sp * C + lbase);
        float t0 = -cs.x, t1 = -cs.y, t2 = -cs.z, t3 = -cs.w;
        float m1v[4][4];

        #pragma unroll
        for (int dd = 0; dd < 4; ++dd) {
            int sx, sy;
            const bool bnd = sender_of(gx, gy, dd, sx, sy) && !INTERIOR;
            float u0 = 0.f, u1 = 0.f, u2 = 0.f, u3 = 0.f;
            if (INTERIOR || !bnd) {
                const float4 c2 = *(const float4*)(prob_vol + (sy * W + sx) * C + lbase);
                const float wgt = edge[dd * HW + sp];
                const float A0  = aff[(dd * 3 + 0) * HW + sp];
                const float A1  = aff[(dd * 3 + 1) * HW + sp];
                const float L2c = aff[(dd * 3 + 2) * HW + sp];
                const float am1 = ((dd & 1) == 0) ? A0 : A1;
                const float ap1 = ((dd & 1) == 0) ? A1 : A0;
                msg_core<false>(-c2.x, -c2.y, -c2.z, -c2.w, q,
                                wgt * ap1, wgt * am1, wgt * L2c,
                                u0, u1, u2, u3);
            }
            m1v[dd][0] = u0; m1v[dd][1] = u1; m1v[dd][2] = u2; m1v[dd][3] = u3;
            t0 += u0; t1 += u1; t2 += u2; t3 += u3;
        }

        #pragma unroll
        for (int dd = 0; dd < 4; ++dd) {
            const int rx = gx + ((dd == 0) ? -1 : (dd == 1) ? 1 : 0);
            const int ry = gy + ((dd == 2) ? -1 : (dd == 3) ? 1 : 0);
            const int ex1 = rx - bx0 + 1, ey1 = ry - by0 + 1;
            if (ex1 >= 0 && ex1 < E1 && ey1 >= 0 && ey1 < E1) {
                const int ip = ey1 * E1 + ex1;
                float4 hv;
                hv.x = t0 - m1v[dd][0]; hv.y = t1 - m1v[dd][1];
                hv.z = t2 - m1v[dd][2]; hv.w = t3 - m1v[dd][3];
                *(float4*)&hbuf[((dd ^ 1) * E1 * E1 + ip) * PSTR + lbase] = hv;
            }
        }
    }

    __syncthreads();

    // ---- stage 2: m2 at ext1 (10x10) from LDS h2. sval doubles as m2
    //      storage (store m2, fold t-m2 in place); scatter destinations are
    //      recomputed from tid after the barrier.
    float4 sval[2][4];

    #pragma unroll
    for (int r = 0; r < 2; ++r) {
        const int task = tid + BLOCK * r;
        if (task >= S2_TASKS) break;             // r==1: only tid < 224
        const int e  = task >> 3;
        const int ex = e % E1;
        const int ey = e / E1;
        const int gx = bx0 + ex - 1;
        const int gy = by0 + ey - 1;
        if (!INTERIOR && (gx < 0 || gx >= W || gy < 0 || gy >= H)) continue;

        const int sp = gy * W + gx;
        const float4 cs = *(const float4*)(prob_vol + sp * C + lbase);
        float t0 = -cs.x, t1 = -cs.y, t2 = -cs.z, t3 = -cs.w;

        #pragma unroll
        for (int dd = 0; dd < 4; ++dd) {
            const bool bnd = !INTERIOR &&
                             ((dd == 0 && gx == 0) || (dd == 1 && gx == W - 1) ||
                              (dd == 2 && gy == 0) || (dd == 3 && gy == H - 1));
            float u0 = 0.f, u1 = 0.f, u2 = 0.f, u3 = 0.f;
            if (!bnd) {
                const float4 h4 = *(const float4*)&hbuf[(dd * E1 * E1 + e) * PSTR + lbase];
                const float wgt = edge[dd * HW + sp];
                const float A0  = aff[(dd * 3 + 0) * HW + sp];
                const float A1  = aff[(dd * 3 + 1) * HW + sp];
                const float L2c = aff[(dd * 3 + 2) * HW + sp];
                const float am1 = ((dd & 1) == 0) ? A0 : A1;
                const float ap1 = ((dd & 1) == 0) ? A1 : A0;
                msg_core<false>(h4.x, h4.y, h4.z, h4.w, q,
                                wgt * ap1, wgt * am1, wgt * L2c,
                                u0, u1, u2, u3);
            }
            sval[r][dd].x = u0; sval[r][dd].y = u1;
            sval[r][dd].z = u2; sval[r][dd].w = u3;
            t0 += u0; t1 += u1; t2 += u2; t3 += u3;
        }

        #pragma unroll
        for (int dd = 0; dd < 4; ++dd) {       // fold: sval = t - m2
            sval[r][dd].x = t0 - sval[r][dd].x;
            sval[r][dd].y = t1 - sval[r][dd].y;
            sval[r][dd].z = t2 - sval[r][dd].z;
            sval[r][dd].w = t3 - sval[r][dd].w;
        }
    }

    __syncthreads();   // all h2 reads complete before overwriting with h3

    // scatter h3 = T2 - m2[dd]; destinations recomputed from tid (geometry
    // exactly reproduces the pre-barrier validity conditions).
    #pragma unroll
    for (int r = 0; r < 2; ++r) {
        const int task = tid + BLOCK * r;
        if (task >= S2_TASKS) break;
        const int e  = task >> 3;
        const int ex = e % E1;
        const int ey = e / E1;
        const int gx = bx0 + ex - 1;
        const int gy = by0 + ey - 1;
        if (!INTERIOR && (gx < 0 || gx >= W || gy < 0 || gy >= H)) continue;

        #pragma unroll
        for (int dd = 0; dd < 4; ++dd) {
            const int rx = gx + ((dd == 0) ? -1 : (dd == 1) ? 1 : 0);
            const int ry = gy + ((dd == 2) ? -1 : (dd == 3) ? 1 : 0);
            const int ixr = rx - bx0, iyr = ry - by0;
            if (ixr >= 0 && ixr < TX && iyr >= 0 && iyr < TY) {
                const int dst = (dd ^ 1) * (TX * TY) + iyr * TX + ixr;
                *(float4*)&hbuf[dst * PSTR + lbase] = sval[r][dd];
            }
        }
    }

    __syncthreads();

    // ---- stage 3: m3 + softmax for the inner 8x8 (one pixel per lane-group;
    //      512 of 576 threads active — threads 512+ skip but rejoin at the
    //      caller's loop barrier).
    const int ip = tid >> 3;              // 0..71
    if (ip < TX * TY) {
        const int ix = ip & (TX - 1);
        const int iy = ip >> 3;
        const int gx = bx0 + ix;
        const int gy = by0 + iy;
        const int p  = gy * W + gx;

        float b0 = 0.f, b1 = 0.f, b2 = 0.f, b3 = 0.f;

        #pragma unroll
        for (int d = 0; d < 4; ++d) {
            const bool bnd = !INTERIOR &&
                             ((d == 0 && gx == 0) || (d == 1 && gx == W - 1) ||
                              (d == 2 && gy == 0) || (d == 3 && gy == H - 1));
            float m0 = 0.f, m1 = 0.f, m2v = 0.f, m3v = 0.f;
            if (!bnd) {
                const float4 h4 = *(const float4*)&hbuf[(d * (TX * TY) + ip) * PSTR + lbase];
                const float wgt = edge[d * HW + p];
                const float A0  = aff[(d * 3 + 0) * HW + p];
                const float A1  = aff[(d * 3 + 1) * HW + p];
                const float L2c = aff[(d * 3 + 2) * HW + p];
                const float am1 = ((d & 1) == 0) ? A0 : A1;
                const float ap1 = ((d & 1) == 0) ? A1 : A0;
                msg_core<true>(h4.x, h4.y, h4.z, h4.w, q,
                               wgt * ap1, wgt * am1, wgt * L2c,
                               m0, m1, m2v, m3v);
            }
            nt_store4(msg_out + d * HWC + p * C + lbase, m0, m1, m2v, m3v);
            b0 += m0; b1 += m1; b2 += m2v; b3 += m3v;
        }

        // beliefs = softmax(prob - sum_d m3) over labels
        const float4 cv = *(const float4*)(prob_vol + p * C + lbase);
        float t0 = cv.x - b0, t1 = cv.y - b1, t2 = cv.z - b2, t3 = cv.w - b3;
        float tmax = gmax8(fmaxf(fmaxf(t0, t1), fmaxf(t2, t3)));
        const float e0 = __expf(t0 - tmax), e1 = __expf(t1 - tmax),
                    e2 = __expf(t2 - tmax), e3 = __expf(t3 - tmax);
        float s = gsum8((e0 + e1) + (e2 + e3));
        const float inv = 1.0f / s;
        nt_store4(beliefs + p * C + lbase, e0 * inv, e1 * inv, e2 * inv, e3 * inv);
    }
}

// Persistent kernel: 768 blocks, each loops over a contiguous chunk of tile
// ranks (column-major over the full 80x40 grid, border tiles included via a
// block-uniform template dispatch). Chunk assignment keeps blockIdx & 7
// (the HW XCD round-robin) on contiguous ~12-tile-column panels, preserving
// the L2 locality that got FETCH_SIZE to 22 MB. Exactly 3 blocks/CU resident
// (LDS-capped) with zero dispatch tail.
//
// __launch_bounds__(576, 7): 27 waves/CU = 7 waves on some SIMDs -> VGPR cap
// 73; compiler uses ~40.
__global__ __launch_bounds__(BLOCK, 7) void bp_persist(
    const float* __restrict__ prob_vol, const float* __restrict__ edge,
    const float* __restrict__ aff, float* __restrict__ msg_out,
    float* __restrict__ beliefs)
{
    __shared__ float hbuf[4 * E1 * E1 * PSTR];   // 51,200 B; reused per stage/tile

    const int blk  = blockIdx.x;                 // 0..767
    const int xcd  = blk & 7;
    const int widx = blk >> 3;                   // 0..95
    const int c    = xcd * (NBLK / 8) + widx;    // contiguous chunks per XCD

    const int qt = NTILES / NBLK;                // 4
    const int rt = NTILES % NBLK;                // 128
    const int start = c * qt + ((c < rt) ? c : rt);
    const int cnt   = qt + ((c < rt) ? 1 : 0);   // 4 or 5 tiles

    const int tid = threadIdx.x;

    for (int t = 0; t < cnt; ++t) {
        if (t) __syncthreads();                  // hbuf reuse across tiles

        const int rank = start + t;              // column-major tile rank
        const int col  = rank / NTILE_Y;         // 0..79
        const int row  = rank % NTILE_Y;         // 0..39
        const int bx0  = col * TX;
        const int by0  = row * TY;

        // block-uniform branch: interior iff stage-1 reach is in-bounds
        if (col > 0 && col < NTILE_X - 1 && row > 0 && row < NTILE_Y - 1)
            bp_tile<true >(bx0, by0, tid, prob_vol, edge, aff, msg_out, beliefs, hbuf);
        else
            bp_tile<false>(bx0, by0, tid, prob_vol, edge, aff, msg_out, beliefs, hbuf);
    }
}

extern "C" void kernel_launch(void* const* d_in, const int* in_sizes, int n_in,
                              void* d_out, int out_size, void* d_ws, size_t ws_size,
                              hipStream_t stream) {
    const float* prob_vol = (const float*)d_in[0];
    const float* edge     = (const float*)d_in[1];
    const float* aff      = (const float*)d_in[2];

    float* beliefs_out = (float*)d_out;          // first HWC floats
    float* msg_final   = (float*)d_out + HWC;    // next 4*HWC floats

    bp_persist<<<dim3(NBLK), dim3(BLOCK), 0, stream>>>(
        prob_vol, edge, aff, msg_final, beliefs_out);
}

// Round 6
// 258.432 us; speedup vs baseline: 1.5589x; 1.5589x over previous
//
#include <hip/hip_runtime.h>
#include <math.h>

#define H 320
#define W 640
#define C 32
#define HW (H * W)
#define HWC (H * W * C)
#define FILLV 1e9f

// Tile geometry: 8x8 inner, ext1 = 10x10 (m2 range), ext2 = 12x12 (m1 range).
#define TX 8
#define TY 8
#define E1 10
#define E2 12
#define PSTR 32               // label stride (floats)

#define NTILE_X (W / TX)      // 80
#define NTILE_Y (H / TY)      // 40
#define NTILES (NTILE_X * NTILE_Y)   // 3200
#define NXCD 8
#define RANKS_PER_XCD (NTILES / NXCD)  // 400 (exact: 3200 % 8 == 0)

// ---- DPP cross-lane (VALU pipe) ----
template <int CTRL>
__device__ __forceinline__ float dppf(float x) {
    int r = __builtin_amdgcn_update_dpp(0, __builtin_bit_cast(int, x),
                                        CTRL, 0xF, 0xF, true);
    return __builtin_bit_cast(float, r);
}
#define DPP_XOR1   0xB1    // quad_perm [1,0,3,2]  : lane i <- i^1
#define DPP_XOR2   0x4E    // quad_perm [2,3,0,1]  : lane i <- i^2
#define DPP_MIRR8  0x141   // row_half_mirror      : lane i <- i^7
#define DPP_UP1    0x111   // row_shr:1            : lane i <- i-1
#define DPP_DN1    0x101   // row_shl:1            : lane i <- i+1

__device__ __forceinline__ float gmin8(float v) {
    v = fminf(v, dppf<DPP_XOR1>(v));
    v = fminf(v, dppf<DPP_XOR2>(v));
    v = fminf(v, dppf<DPP_MIRR8>(v));
    return v;
}
__device__ __forceinline__ float gmax8(float v) {
    v = fmaxf(v, dppf<DPP_XOR1>(v));
    v = fmaxf(v, dppf<DPP_XOR2>(v));
    v = fmaxf(v, dppf<DPP_MIRR8>(v));
    return v;
}
__device__ __forceinline__ float gsum8(float v) {
    v += dppf<DPP_XOR1>(v);
    v += dppf<DPP_XOR2>(v);
    v += dppf<DPP_MIRR8>(v);
    return v;
}

// Nontemporal float4 store: keep the 131 MB message/belief write stream from
// evicting the read-side halo working set out of L2.
typedef float vfloat4 __attribute__((ext_vector_type(4)));
__device__ __forceinline__ void nt_store4(float* p, float x, float y, float z, float w) {
    vfloat4 v; v.x = x; v.y = y; v.z = z; v.w = w;
    __builtin_nontemporal_store(v, (vfloat4*)p);
}

// Truncated-linear min-sum core over 32 labels (4/lane x 8 lanes).
// RESCALE subtracts hmin — exact analytic min (weights >= 0). Unrescaled
// intermediates differ from the reference by a per-pixel label-constant,
// which cancels in any downstream rescaled message.
template <bool RESCALE>
__device__ __forceinline__ void msg_core(
    float h0, float h1, float h2, float h3, int q,
    float w_p1, float w_m1, float w_L2,
    float& m0, float& m1, float& m2, float& m3)
{
    const float up = dppf<DPP_UP1>(h3);     // lane q-1's label 4q-1
    const float dn = dppf<DPP_DN1>(h0);     // lane q+1's label 4q+4
    const float lm0 = (q == 0) ? FILLV : up;
    const float lp3 = (q == 7) ? FILLV : dn;

    float hmin = gmin8(fminf(fminf(h0, h1), fminf(h2, h3)));
    const float tr = hmin + w_L2;
    const float sub = RESCALE ? hmin : 0.f;

    m0 = fminf(fminf(h0, lm0 + w_p1), fminf(h1 + w_m1, tr)) - sub;
    m1 = fminf(fminf(h1, h0  + w_p1), fminf(h2 + w_m1, tr)) - sub;
    m2 = fminf(fminf(h2, h1  + w_p1), fminf(h3 + w_m1, tr)) - sub;
    m3 = fminf(fminf(h3, h2  + w_p1), fminf(lp3 + w_m1, tr)) - sub;
}

// d: 0 -> sender at x-1 (boundary x==0), 1 -> x+1, 2 -> y-1, 3 -> y+1.
__device__ __forceinline__ bool sender_of(int x, int y, int d, int& sx, int& sy) {
    sx = x; sy = y;
    if (d == 0) { sx = x - 1; return x == 0; }
    if (d == 1) { sx = x + 1; return x == W - 1; }
    if (d == 2) { sy = y - 1; return y == 0; }
    sy = y + 1; return y == H - 1;
}

// Shared tile pipeline — identical to the round-3 (78 us measured) version.
// INTERIOR=true compiles away every OOB / image-border guard (valid whenever
// the tile's stage-1 reach [bx0-3,bx0+10]x[by0-3,by0+10] is in-bounds).
template <bool INTERIOR>
__device__ __forceinline__ void bp_tile(
    const int bx0, const int by0,
    const float* __restrict__ prob_vol, const float* __restrict__ edge,
    const float* __restrict__ aff, float* __restrict__ msg_out,
    float* __restrict__ beliefs, float* hbuf)
{
    const int tid = threadIdx.x;
    const int q = tid & 7;
    const int lbase = 4 * q;

    // ---- stage 1: m1 at ext2 (12x12), scatter h2 = T1 - m1[dd] to the
    //      ext1 receiver in direction dd (plane dd^1).
    #pragma unroll
    for (int pass = 0; pass < 3; ++pass) {
        const int task = tid + 512 * pass;
        if (task >= E2 * E2 * 8) break;          // only pass 2 is partial
        const int e  = task >> 3;
        const int ex = e % E2;
        const int ey = e / E2;
        const int gx = bx0 + ex - 2;
        const int gy = by0 + ey - 2;
        if (!INTERIOR && (gx < 0 || gx >= W || gy < 0 || gy >= H)) continue;

        const int sp = gy * W + gx;
        const float4 cs = *(const float4*)(prob_vol + sp * C + lbase);
        float t0 = -cs.x, t1 = -cs.y, t2 = -cs.z, t3 = -cs.w;
        float m1v[4][4];

        #pragma unroll
        for (int dd = 0; dd < 4; ++dd) {
            int sx, sy;
            const bool bnd = sender_of(gx, gy, dd, sx, sy) && !INTERIOR;
            float u0 = 0.f, u1 = 0.f, u2 = 0.f, u3 = 0.f;
            if (INTERIOR || !bnd) {
                const float4 c2 = *(const float4*)(prob_vol + (sy * W + sx) * C + lbase);
                const float wgt = edge[dd * HW + sp];
                const float A0  = aff[(dd * 3 + 0) * HW + sp];
                const float A1  = aff[(dd * 3 + 1) * HW + sp];
                const float L2c = aff[(dd * 3 + 2) * HW + sp];
                const float am1 = ((dd & 1) == 0) ? A0 : A1;
                const float ap1 = ((dd & 1) == 0) ? A1 : A0;
                msg_core<false>(-c2.x, -c2.y, -c2.z, -c2.w, q,
                                wgt * ap1, wgt * am1, wgt * L2c,
                                u0, u1, u2, u3);
            }
            m1v[dd][0] = u0; m1v[dd][1] = u1; m1v[dd][2] = u2; m1v[dd][3] = u3;
            t0 += u0; t1 += u1; t2 += u2; t3 += u3;
        }

        #pragma unroll
        for (int dd = 0; dd < 4; ++dd) {
            const int rx = gx + ((dd == 0) ? -1 : (dd == 1) ? 1 : 0);
            const int ry = gy + ((dd == 2) ? -1 : (dd == 3) ? 1 : 0);
            const int ex1 = rx - bx0 + 1, ey1 = ry - by0 + 1;
            if (ex1 >= 0 && ex1 < E1 && ey1 >= 0 && ey1 < E1) {
                const int ip = ey1 * E1 + ex1;
                float4 hv;
                hv.x = t0 - m1v[dd][0]; hv.y = t1 - m1v[dd][1];
                hv.z = t2 - m1v[dd][2]; hv.w = t3 - m1v[dd][3];
                *(float4*)&hbuf[((dd ^ 1) * E1 * E1 + ip) * PSTR + lbase] = hv;
            }
        }
    }

    __syncthreads();

    // ---- stage 2: m2 at ext1 (10x10) from LDS h2. sval doubles as m2
    //      storage (store m2, fold t-m2 in place); scatter destinations are
    //      recomputed from tid after the barrier.
    float4 sval[2][4];

    #pragma unroll
    for (int r = 0; r < 2; ++r) {
        const int task = tid + 512 * r;
        if (task >= E1 * E1 * 8) break;
        const int e  = task >> 3;
        const int ex = e % E1;
        const int ey = e / E1;
        const int gx = bx0 + ex - 1;
        const int gy = by0 + ey - 1;
        if (!INTERIOR && (gx < 0 || gx >= W || gy < 0 || gy >= H)) continue;

        const int sp = gy * W + gx;
        const float4 cs = *(const float4*)(prob_vol + sp * C + lbase);
        float t0 = -cs.x, t1 = -cs.y, t2 = -cs.z, t3 = -cs.w;

        #pragma unroll
        for (int dd = 0; dd < 4; ++dd) {
            const bool bnd = !INTERIOR &&
                             ((dd == 0 && gx == 0) || (dd == 1 && gx == W - 1) ||
                              (dd == 2 && gy == 0) || (dd == 3 && gy == H - 1));
            float u0 = 0.f, u1 = 0.f, u2 = 0.f, u3 = 0.f;
            if (!bnd) {
                const float4 h4 = *(const float4*)&hbuf[(dd * E1 * E1 + e) * PSTR + lbase];
                const float wgt = edge[dd * HW + sp];
                const float A0  = aff[(dd * 3 + 0) * HW + sp];
                const float A1  = aff[(dd * 3 + 1) * HW + sp];
                const float L2c = aff[(dd * 3 + 2) * HW + sp];
                const float am1 = ((dd & 1) == 0) ? A0 : A1;
                const float ap1 = ((dd & 1) == 0) ? A1 : A0;
                msg_core<false>(h4.x, h4.y, h4.z, h4.w, q,
                                wgt * ap1, wgt * am1, wgt * L2c,
                                u0, u1, u2, u3);
            }
            sval[r][dd].x = u0; sval[r][dd].y = u1;
            sval[r][dd].z = u2; sval[r][dd].w = u3;
            t0 += u0; t1 += u1; t2 += u2; t3 += u3;
        }

        #pragma unroll
        for (int dd = 0; dd < 4; ++dd) {       // fold: sval = t - m2
            sval[r][dd].x = t0 - sval[r][dd].x;
            sval[r][dd].y = t1 - sval[r][dd].y;
            sval[r][dd].z = t2 - sval[r][dd].z;
            sval[r][dd].w = t3 - sval[r][dd].w;
        }
    }

    __syncthreads();   // all h2 reads complete before overwriting with h3

    // scatter h3 = T2 - m2[dd]; destinations recomputed from tid (geometry
    // exactly reproduces the pre-barrier validity conditions).
    #pragma unroll
    for (int r = 0; r < 2; ++r) {
        const int task = tid + 512 * r;
        if (task >= E1 * E1 * 8) break;
        const int e  = task >> 3;
        const int ex = e % E1;
        const int ey = e / E1;
        const int gx = bx0 + ex - 1;
        const int gy = by0 + ey - 1;
        if (!INTERIOR && (gx < 0 || gx >= W || gy < 0 || gy >= H)) continue;

        #pragma unroll
        for (int dd = 0; dd < 4; ++dd) {
            const int rx = gx + ((dd == 0) ? -1 : (dd == 1) ? 1 : 0);
            const int ry = gy + ((dd == 2) ? -1 : (dd == 3) ? 1 : 0);
            const int ixr = rx - bx0, iyr = ry - by0;
            if (ixr >= 0 && ixr < TX && iyr >= 0 && iyr < TY) {
                const int dst = (dd ^ 1) * (TX * TY) + iyr * TX + ixr;
                *(float4*)&hbuf[dst * PSTR + lbase] = sval[r][dd];
            }
        }
    }

    __syncthreads();

    // ---- stage 3: m3 + softmax for the inner 8x8 (one pixel per lane-group)
    const int ip = tid >> 3;              // 0..63
    const int ix = ip & (TX - 1);
    const int iy = ip >> 3;
    const int gx = bx0 + ix;
    const int gy = by0 + iy;
    const int p  = gy * W + gx;

    float b0 = 0.f, b1 = 0.f, b2 = 0.f, b3 = 0.f;

    #pragma unroll
    for (int d = 0; d < 4; ++d) {
        const bool bnd = !INTERIOR &&
                         ((d == 0 && gx == 0) || (d == 1 && gx == W - 1) ||
                          (d == 2 && gy == 0) || (d == 3 && gy == H - 1));
        float m0 = 0.f, m1 = 0.f, m2v = 0.f, m3v = 0.f;
        if (!bnd) {
            const float4 h4 = *(const float4*)&hbuf[(d * (TX * TY) + ip) * PSTR + lbase];
            const float wgt = edge[d * HW + p];
            const float A0  = aff[(d * 3 + 0) * HW + p];
            const float A1  = aff[(d * 3 + 1) * HW + p];
            const float L2c = aff[(d * 3 + 2) * HW + p];
            const float am1 = ((d & 1) == 0) ? A0 : A1;
            const float ap1 = ((d & 1) == 0) ? A1 : A0;
            msg_core<true>(h4.x, h4.y, h4.z, h4.w, q,
                           wgt * ap1, wgt * am1, wgt * L2c,
                           m0, m1, m2v, m3v);
        }
        nt_store4(msg_out + d * HWC + p * C + lbase, m0, m1, m2v, m3v);
        b0 += m0; b1 += m1; b2 += m2v; b3 += m3v;
    }

    // beliefs = softmax(prob - sum_d m3) over labels
    const float4 cv = *(const float4*)(prob_vol + p * C + lbase);
    float t0 = cv.x - b0, t1 = cv.y - b1, t2 = cv.z - b2, t3 = cv.w - b3;
    float tmax = gmax8(fmaxf(fmaxf(t0, t1), fmaxf(t2, t3)));
    const float e0 = __expf(t0 - tmax), e1 = __expf(t1 - tmax),
                e2 = __expf(t2 - tmax), e3 = __expf(t3 - tmax);
    float s = gsum8((e0 + e1) + (e2 + e3));
    const float inv = 1.0f / s;
    nt_store4(beliefs + p * C + lbase, e0 * inv, e1 * inv, e2 * inv, e3 * inv);
}

// Single launch, one block per tile (round-3 geometry, which measured 78 us /
// FETCH 22 MB for the interior), with the border ring folded in as a
// block-uniform template dispatch — removes the serialized bp_border drain
// and the second launch. NOT persistent: round 4 showed a persistent grid
// spreads the instantaneous per-XCD footprint over the whole ~10-column panel
// (~4.8 MB > 4 MB L2 -> FETCH 6x, VALUBusy 19%). Per-tile blocks restore the
// dispatch-order sliding window (~67 consecutive tiles per XCD, ~0.9 MB).
//
// XCD swizzle (exact: 3200 % 8 == 0): xcd = blk&7 (HW round-robin), rank =
// xcd*400 + blk>>3, column-major rank -> each XCD owns 10 contiguous
// tile-columns.
__global__ __launch_bounds__(512, 4) void bp_all(
    const float* __restrict__ prob_vol, const float* __restrict__ edge,
    const float* __restrict__ aff, float* __restrict__ msg_out,
    float* __restrict__ beliefs)
{
    __shared__ float hbuf[4 * E1 * E1 * PSTR];   // 51,200 B; reused for h3

    const int blk  = blockIdx.x;                 // 0..3199
    const int rank = (blk & (NXCD - 1)) * RANKS_PER_XCD + (blk >> 3);
    const int col  = rank / NTILE_Y;             // 0..79
    const int row  = rank % NTILE_Y;             // 0..39
    const int bx0  = col * TX;
    const int by0  = row * TY;

    // block-uniform branch: interior iff stage-1 reach is in-bounds
    if (col > 0 && col < NTILE_X - 1 && row > 0 && row < NTILE_Y - 1)
        bp_tile<true >(bx0, by0, prob_vol, edge, aff, msg_out, beliefs, hbuf);
    else
        bp_tile<false>(bx0, by0, prob_vol, edge, aff, msg_out, beliefs, hbuf);
}

extern "C" void kernel_launch(void* const* d_in, const int* in_sizes, int n_in,
                              void* d_out, int out_size, void* d_ws, size_t ws_size,
                              hipStream_t stream) {
    const float* prob_vol = (const float*)d_in[0];
    const float* edge     = (const float*)d_in[1];
    const float* aff      = (const float*)d_in[2];

    float* beliefs_out = (float*)d_out;          // first HWC floats
    float* msg_final   = (float*)d_out + HWC;    // next 4*HWC floats

    bp_all<<<dim3(NTILES), dim3(512), 0, stream>>>(
        prob_vol, edge, aff, msg_final, beliefs_out);
}